// Round 1
// baseline (148061.511 us; speedup 1.0000x reference)
//
#include <hip/hip_runtime.h>
#include <cstdint>
#include <cstddef>

// Problem constants
#define B_ 64
#define S_ 2048
#define F_ 128
#define H_ 512
#define GEN_SZ 16777216ull  // B*S*F
#define HO1 16777216ull
#define CO1 16809984ull
#define HO2 16842752ull
#define CO2 16875520ull

typedef __bf16 bf16_t;
typedef __attribute__((ext_vector_type(8))) __bf16 bf16x8;
typedef __attribute__((ext_vector_type(4))) float f32x4;
typedef __attribute__((ext_vector_type(8))) unsigned short u16x8;

// ---- workspace layout (bytes) ----
#define OFF_CNT   0ull        // 4 counters, 128B apart
#define OFF_PG    1024ull     // prev_gen0 bf16 [64][128]
#define OFF_H1    17408ull    // h1 double buffer bf16 [2][64][512]
#define OFF_H2    148480ull   // h2 double buffer bf16 [2][64][512]
#define OFF_OUT   279552ull   // fc1 'out' bf16 [64][512]
#define OFF_B1P   345088ull   // fused bias1' fp32 [512]
#define OFF_WF    347136ull   // Wfused fp32 [512][512]
#define OFF_FRAG  1395712ull  // fragment heap (9984 frags x 1KiB)
// frag region bases (units of 1 frag = 64 lanes * 16B = 1KiB)
#define FR_S2   0
#define FR_S3   4096
#define FR_S1   8192
#define FR_S1T0 9472
#define FR_TOTAL 9984

__device__ __forceinline__ float sigm(float x) { return 1.f / (1.f + __expf(-x)); }
__device__ __forceinline__ float tanh_(float x) { return 2.f / (1.f + __expf(-2.f * x)) - 1.f; }

// ---------------- prep: init small buffers ----------------
__global__ void k_init(const float* __restrict__ pg0, const float* __restrict__ h1i,
                       const float* __restrict__ h2i, uint8_t* __restrict__ ws) {
    int idx = blockIdx.x * 256 + threadIdx.x;
    if (idx < 4) ((unsigned int*)(ws + OFF_CNT))[idx * 32] = 0u;
    if (idx < B_ * F_) ((bf16_t*)(ws + OFF_PG))[idx] = (bf16_t)pg0[idx];
    if (idx < B_ * H_) {
        ((bf16_t*)(ws + OFF_H1))[B_ * H_ + idx] = (bf16_t)h1i[idx];  // buffer 1 = "t=-1"
        ((bf16_t*)(ws + OFF_H2))[B_ * H_ + idx] = (bf16_t)h2i[idx];
    }
}

// ---------------- prep: Wfused = W_fc1[:,128:256] @ W_fc2  (and bias1') ----------------
__global__ void k_fuse(const float* __restrict__ Wfc1, const float* __restrict__ bfc1,
                       const float* __restrict__ Wfc2, const float* __restrict__ bfc2,
                       uint8_t* __restrict__ ws) {
    int o = blockIdx.x;      // 0..511
    int t = threadIdx.x;     // 0..127
    __shared__ float wrow[128];
    wrow[t] = Wfc1[o * 256 + 128 + t];
    __syncthreads();
    float* WF = (float*)(ws + OFF_WF);
    f32x4 s = {0.f, 0.f, 0.f, 0.f};
    for (int m = 0; m < 128; ++m) {
        f32x4 b = *(const f32x4*)(Wfc2 + m * 512 + t * 4);
        float w = wrow[m];
        s[0] += w * b[0]; s[1] += w * b[1]; s[2] += w * b[2]; s[3] += w * b[3];
    }
    *(f32x4*)(WF + o * 512 + t * 4) = s;
    if (t == 0) {
        float sb = bfc1[o];
        for (int m = 0; m < 128; ++m) sb += wrow[m] * bfc2[m];
        ((float*)(ws + OFF_B1P))[o] = sb;
    }
}

// ---------------- prep: build MFMA B-fragments for all stages ----------------
__global__ void k_frags(const float* __restrict__ Wfc1, const float* __restrict__ Wih1,
                        const float* __restrict__ Whh1, const float* __restrict__ Wih2,
                        const float* __restrict__ Whh2, const float* __restrict__ Wfc2,
                        uint8_t* __restrict__ ws) {
    int gid = blockIdx.x * 256 + threadIdx.x;  // exactly FR_TOTAL*64 threads
    int fid = gid >> 6;
    int lane = gid & 63;
    int n16 = lane & 15, quad = lane >> 4;
    const float* WF = (const float*)(ws + OFF_WF);
    u16x8 pk;
#pragma unroll
    for (int j = 0; j < 8; ++j) {
        float v = 0.f;
        if (fid < 4096) {  // stage2 (LSTM1): in=[out|h1] K=1024, 32 gate-cols per WG
            int tl = fid & 1, ki = (fid >> 1) & 7, wv = (fid >> 4) & 3, wg = fid >> 6;
            int n32 = tl * 16 + n16; int j8 = n32 & 7; int gate = n32 >> 3;
            int R = gate * 512 + wg * 8 + j8;
            int k = wv * 256 + ki * 32 + quad * 8 + j;
            v = (k < 512) ? Wih1[R * 512 + k] : Whh1[R * 512 + k - 512];
        } else if (fid < 8192) {  // stage3 (LSTM2): in=[h1n|h2]
            int f2 = fid - 4096;
            int tl = f2 & 1, ki = (f2 >> 1) & 7, wv = (f2 >> 4) & 3, wg = f2 >> 6;
            int n32 = tl * 16 + n16; int j8 = n32 & 7; int gate = n32 >> 3;
            int R = gate * 512 + wg * 8 + j8;
            int k = wv * 256 + ki * 32 + quad * 8 + j;
            v = (k < 512) ? Wih2[R * 512 + k] : Whh2[R * 512 + k - 512];
        } else if (fid < 9472) {  // stage1 fused (t>=1): in=[x|h2p] K=640, cols=[out(8)|gen(2)|pad]
            int f2 = fid - 8192;
            int ki = f2 % 5; int wv = (f2 / 5) & 3; int wg = f2 / 20;
            int k = wv * 160 + ki * 32 + quad * 8 + j;
            if (n16 < 8) {
                int o = wg * 8 + n16;
                v = (k < 128) ? Wfc1[o * 256 + k] : WF[o * 512 + (k - 128)];
            } else if (n16 < 10) {
                int m = wg * 2 + (n16 - 8);
                v = (k < 128) ? 0.f : Wfc2[m * 512 + (k - 128)];
            }
        } else {  // stage1 at t==0: in=[x0|prev_gen0] K=256, W_fc1 direct
            int f2 = fid - 9472;
            int ki = f2 & 1; int wv = (f2 >> 1) & 3; int wg = f2 >> 3;
            int k = wv * 64 + ki * 32 + quad * 8 + j;
            if (n16 < 8) v = Wfc1[(wg * 8 + n16) * 256 + k];
        }
        bf16_t bb = (bf16_t)v;
        pk[j] = __builtin_bit_cast(unsigned short, bb);
    }
    *((u16x8*)(ws + OFF_FRAG) + (size_t)fid * 64 + lane) = pk;
}

// ---------------- group barrier (64 WGs of one batch-group) ----------------
__device__ __forceinline__ void gbar(unsigned int* cnt, unsigned int target) {
    __builtin_amdgcn_fence(__ATOMIC_RELEASE, "agent");
    __syncthreads();
    if (threadIdx.x == 0) {
        __hip_atomic_fetch_add(cnt, 1u, __ATOMIC_RELAXED, __HIP_MEMORY_SCOPE_AGENT);
        while (__hip_atomic_load(cnt, __ATOMIC_RELAXED, __HIP_MEMORY_SCOPE_AGENT) < target) {}
    }
    __syncthreads();
    __builtin_amdgcn_fence(__ATOMIC_ACQUIRE, "agent");
}

// ---------------- persistent recurrence kernel ----------------
// grid = 256 WGs: blockIdx = g*64 + wg  (g: batch-group 0..3 -> rows g*16..g*16+15;
// wg: column-group 0..63). 256 threads = 4 waves; weights live in VGPRs.
__launch_bounds__(256, 1)
__global__ void k_rnn(const float* __restrict__ x, const float* __restrict__ c1i,
                      const float* __restrict__ c2i, const float* __restrict__ bfc1,
                      const float* __restrict__ b1, const float* __restrict__ b2g,
                      const float* __restrict__ bfc2, uint8_t* __restrict__ ws,
                      float* __restrict__ out) {
    const int wg = blockIdx.x & 63;
    const int g = blockIdx.x >> 6;
    const int tid = threadIdx.x;
    const int wave = tid >> 6, lane = tid & 63;
    const int quad = lane >> 4, row16 = lane & 15;
    const int b_ = g * 16 + row16;

    bf16_t* pg = (bf16_t*)(ws + OFF_PG);
    bf16_t* h1b = (bf16_t*)(ws + OFF_H1);
    bf16_t* h2b = (bf16_t*)(ws + OFF_H2);
    bf16_t* outb = (bf16_t*)(ws + OFF_OUT);
    const float* b1p = (const float*)(ws + OFF_B1P);
    unsigned int* cnt = (unsigned int*)(ws + OFF_CNT) + g * 32;
    const u16x8* heap = (const u16x8*)(ws + OFF_FRAG);

    // ---- load all weight fragments into registers (stationary for all 2048 steps) ----
    bf16x8 fr2[16], fr3[16], fr1[5], fr10[2];
    const int wslot = wg * 4 + wave;
#pragma unroll
    for (int f = 0; f < 16; ++f)
        fr2[f] = __builtin_bit_cast(bf16x8, heap[(size_t)(FR_S2 + wslot * 16 + f) * 64 + lane]);
#pragma unroll
    for (int f = 0; f < 16; ++f)
        fr3[f] = __builtin_bit_cast(bf16x8, heap[(size_t)(FR_S3 + wslot * 16 + f) * 64 + lane]);
#pragma unroll
    for (int f = 0; f < 5; ++f)
        fr1[f] = __builtin_bit_cast(bf16x8, heap[(size_t)(FR_S1 + wslot * 5 + f) * 64 + lane]);
#pragma unroll
    for (int f = 0; f < 2; ++f)
        fr10[f] = __builtin_bit_cast(bf16x8, heap[(size_t)(FR_S1T0 + wslot * 2 + f) * 64 + lane]);

    __shared__ float red[4][2][16][16];
    __shared__ float gbuf[16][32];
    __shared__ float cb1[16][8], cb2[16][8];

    // per-thread biases for the reduction step: (rrow, rc) covers the 16x16 D-tile
    const int rrow = tid >> 4, rc = tid & 15;
    const float bias2_a = b1[(rc >> 3) * 512 + wg * 8 + (rc & 7)];
    const float bias2_b = b1[(2 + (rc >> 3)) * 512 + wg * 8 + (rc & 7)];
    const float bias3_a = b2g[(rc >> 3) * 512 + wg * 8 + (rc & 7)];
    const float bias3_b = b2g[(2 + (rc >> 3)) * 512 + wg * 8 + (rc & 7)];
    const float bias1 = (rc < 8) ? b1p[wg * 8 + rc] : ((rc < 10) ? bfc2[wg * 2 + rc - 8] : 0.f);
    const float bias1t0 = (rc < 8) ? bfc1[wg * 8 + rc] : 0.f;

    if (tid < 128) {  // cell state stays local (fp32) for the whole sequence
        int r = tid >> 3, j = tid & 7;
        cb1[r][j] = c1i[(g * 16 + r) * 512 + wg * 8 + j];
        cb2[r][j] = c2i[(g * 16 + r) * 512 + wg * 8 + j];
    }
    __syncthreads();

    unsigned int bt = 0;

#pragma clang loop unroll(disable)
    for (int t = 0; t <= S_; ++t) {
        const int cbuf = t & 1, pbuf = cbuf ^ 1;

        // ============ P1: out = relu([x_t | h2p] @ W1') ; gen(t-1) = extra cols ============
        {
            f32x4 acc = {0.f, 0.f, 0.f, 0.f};
            if (t == 0) {
#pragma unroll
                for (int ki = 0; ki < 2; ++ki) {
                    int k = wave * 64 + ki * 32 + quad * 8;
                    bf16x8 a;
                    if (k < 128) {
                        const float* xp = x + ((size_t)b_ * S_) * F_ + k;
                        f32x4 x0 = *(const f32x4*)xp, x1 = *(const f32x4*)(xp + 4);
#pragma unroll
                        for (int i = 0; i < 4; ++i) { a[i] = (bf16_t)x0[i]; a[4 + i] = (bf16_t)x1[i]; }
                    } else {
                        a = *(const bf16x8*)(pg + (size_t)b_ * 128 + (k - 128));
                    }
                    acc = __builtin_amdgcn_mfma_f32_16x16x32_bf16(a, fr10[ki], acc, 0, 0, 0);
                }
            } else {
                const int tx = (t < S_) ? t : (S_ - 1);  // t==S_: x part hits zero weights
                const bf16_t* h2p = h2b + (size_t)pbuf * (B_ * H_);
#pragma unroll
                for (int ki = 0; ki < 5; ++ki) {
                    int k = wave * 160 + ki * 32 + quad * 8;
                    bf16x8 a;
                    if (k < 128) {
                        const float* xp = x + ((size_t)b_ * S_ + tx) * F_ + k;
                        f32x4 x0 = *(const f32x4*)xp, x1 = *(const f32x4*)(xp + 4);
#pragma unroll
                        for (int i = 0; i < 4; ++i) { a[i] = (bf16_t)x0[i]; a[4 + i] = (bf16_t)x1[i]; }
                    } else {
                        a = *(const bf16x8*)(h2p + (size_t)b_ * H_ + (k - 128));
                    }
                    acc = __builtin_amdgcn_mfma_f32_16x16x32_bf16(a, fr1[ki], acc, 0, 0, 0);
                }
            }
#pragma unroll
            for (int i = 0; i < 4; ++i) red[wave][0][quad * 4 + i][row16] = acc[i];
            __syncthreads();
            float v = red[0][0][rrow][rc] + red[1][0][rrow][rc] + red[2][0][rrow][rc] +
                      red[3][0][rrow][rc];
            if (t == 0) {
                if (rc < 8) {
                    v = fmaxf(v + bias1t0, 0.f);
                    outb[(size_t)(g * 16 + rrow) * H_ + wg * 8 + rc] = (bf16_t)v;
                }
            } else if (rc < 8) {
                if (t < S_) {
                    v = fmaxf(v + bias1, 0.f);
                    outb[(size_t)(g * 16 + rrow) * H_ + wg * 8 + rc] = (bf16_t)v;
                }
            } else if (rc < 10) {  // gen(t-1) -> d_out (fp32)
                out[(size_t)(g * 16 + rrow) * (S_ * F_) + (size_t)(t - 1) * F_ + wg * 2 + (rc - 8)] =
                    v + bias1;
            }
        }
        if (t == S_) break;  // last gen written; done
        gbar(cnt, bt += 64);

        // ============ P2: LSTM1 gates = [out | h1(t-1)] @ W ; update c1, h1n ============
        {
            const bf16_t* h1p = h1b + (size_t)pbuf * (B_ * H_);
            const bf16_t* asrc = (wave < 2) ? (outb + (size_t)b_ * H_ + wave * 256)
                                            : (h1p + (size_t)b_ * H_ + (wave - 2) * 256);
            const bf16x8* ap = (const bf16x8*)(asrc + quad * 8);
            f32x4 acc0 = {0.f, 0.f, 0.f, 0.f}, acc1 = {0.f, 0.f, 0.f, 0.f};
#pragma unroll
            for (int ki = 0; ki < 8; ++ki) {
                bf16x8 a = ap[ki * 4];
                acc0 = __builtin_amdgcn_mfma_f32_16x16x32_bf16(a, fr2[ki * 2 + 0], acc0, 0, 0, 0);
                acc1 = __builtin_amdgcn_mfma_f32_16x16x32_bf16(a, fr2[ki * 2 + 1], acc1, 0, 0, 0);
            }
#pragma unroll
            for (int i = 0; i < 4; ++i) {
                red[wave][0][quad * 4 + i][row16] = acc0[i];
                red[wave][1][quad * 4 + i][row16] = acc1[i];
            }
            __syncthreads();
            float v0 = red[0][0][rrow][rc] + red[1][0][rrow][rc] + red[2][0][rrow][rc] +
                       red[3][0][rrow][rc] + bias2_a;
            float v1 = red[0][1][rrow][rc] + red[1][1][rrow][rc] + red[2][1][rrow][rc] +
                       red[3][1][rrow][rc] + bias2_b;
            gbuf[rrow][rc] = v0;       // cols 0..15: i,f
            gbuf[rrow][rc + 16] = v1;  // cols 16..31: g,o
            __syncthreads();
            if (tid < 128) {
                int r = tid >> 3, j = tid & 7;
                float gi = gbuf[r][j], gf = gbuf[r][8 + j], gg = gbuf[r][16 + j], go = gbuf[r][24 + j];
                float cn = sigm(gf) * cb1[r][j] + sigm(gi) * tanh_(gg);
                cb1[r][j] = cn;
                float h = sigm(go) * tanh_(cn);
                h1b[(size_t)cbuf * (B_ * H_) + (size_t)(g * 16 + r) * H_ + wg * 8 + j] = (bf16_t)h;
                if (t == S_ - 1) {
                    out[HO1 + (size_t)(g * 16 + r) * H_ + wg * 8 + j] = h;
                    out[CO1 + (size_t)(g * 16 + r) * H_ + wg * 8 + j] = cn;
                }
            }
        }
        gbar(cnt, bt += 64);

        // ============ P3: LSTM2 gates = [h1n | h2(t-1)] @ W ; update c2, h2n ============
        {
            const bf16_t* h1c = h1b + (size_t)cbuf * (B_ * H_);
            const bf16_t* h2p = h2b + (size_t)pbuf * (B_ * H_);
            const bf16_t* asrc = (wave < 2) ? (h1c + (size_t)b_ * H_ + wave * 256)
                                            : (h2p + (size_t)b_ * H_ + (wave - 2) * 256);
            const bf16x8* ap = (const bf16x8*)(asrc + quad * 8);
            f32x4 acc0 = {0.f, 0.f, 0.f, 0.f}, acc1 = {0.f, 0.f, 0.f, 0.f};
#pragma unroll
            for (int ki = 0; ki < 8; ++ki) {
                bf16x8 a = ap[ki * 4];
                acc0 = __builtin_amdgcn_mfma_f32_16x16x32_bf16(a, fr3[ki * 2 + 0], acc0, 0, 0, 0);
                acc1 = __builtin_amdgcn_mfma_f32_16x16x32_bf16(a, fr3[ki * 2 + 1], acc1, 0, 0, 0);
            }
#pragma unroll
            for (int i = 0; i < 4; ++i) {
                red[wave][0][quad * 4 + i][row16] = acc0[i];
                red[wave][1][quad * 4 + i][row16] = acc1[i];
            }
            __syncthreads();
            float v0 = red[0][0][rrow][rc] + red[1][0][rrow][rc] + red[2][0][rrow][rc] +
                       red[3][0][rrow][rc] + bias3_a;
            float v1 = red[0][1][rrow][rc] + red[1][1][rrow][rc] + red[2][1][rrow][rc] +
                       red[3][1][rrow][rc] + bias3_b;
            gbuf[rrow][rc] = v0;
            gbuf[rrow][rc + 16] = v1;
            __syncthreads();
            if (tid < 128) {
                int r = tid >> 3, j = tid & 7;
                float gi = gbuf[r][j], gf = gbuf[r][8 + j], gg = gbuf[r][16 + j], go = gbuf[r][24 + j];
                float cn = sigm(gf) * cb2[r][j] + sigm(gi) * tanh_(gg);
                cb2[r][j] = cn;
                float h = sigm(go) * tanh_(cn);
                h2b[(size_t)cbuf * (B_ * H_) + (size_t)(g * 16 + r) * H_ + wg * 8 + j] = (bf16_t)h;
                if (t == S_ - 1) {
                    out[HO2 + (size_t)(g * 16 + r) * H_ + wg * 8 + j] = h;
                    out[CO2 + (size_t)(g * 16 + r) * H_ + wg * 8 + j] = cn;
                }
            }
        }
        gbar(cnt, bt += 64);
    }
}

extern "C" void kernel_launch(void* const* d_in, const int* in_sizes, int n_in, void* d_out,
                              int out_size, void* d_ws, size_t ws_size, hipStream_t stream) {
    const float* x = (const float*)d_in[0];
    const float* pg0 = (const float*)d_in[1];
    const float* h1i = (const float*)d_in[2];
    const float* c1i = (const float*)d_in[3];
    const float* h2i = (const float*)d_in[4];
    const float* c2i = (const float*)d_in[5];
    const float* Wfc1 = (const float*)d_in[6];
    const float* bfc1 = (const float*)d_in[7];
    const float* Wih1 = (const float*)d_in[8];
    const float* Whh1 = (const float*)d_in[9];
    const float* b1 = (const float*)d_in[10];
    const float* Wih2 = (const float*)d_in[11];
    const float* Whh2 = (const float*)d_in[12];
    const float* b2g = (const float*)d_in[13];
    const float* Wfc2 = (const float*)d_in[14];
    const float* bfc2 = (const float*)d_in[15];
    uint8_t* ws = (uint8_t*)d_ws;
    float* out = (float*)d_out;

    k_init<<<dim3(128), dim3(256), 0, stream>>>(pg0, h1i, h2i, ws);
    k_fuse<<<dim3(512), dim3(128), 0, stream>>>(Wfc1, bfc1, Wfc2, bfc2, ws);
    k_frags<<<dim3(2496), dim3(256), 0, stream>>>(Wfc1, Wih1, Whh1, Wih2, Whh2, Wfc2, ws);
    k_rnn<<<dim3(256), dim3(256), 0, stream>>>(x, c1i, c2i, bfc1, b1, b2g, bfc2, ws, out);
}

// Round 2
// 28719.318 us; speedup vs baseline: 5.1555x; 5.1555x over previous
//
#include <hip/hip_runtime.h>
#include <cstdint>
#include <cstddef>

// Problem constants
#define B_ 64
#define S_ 2048
#define F_ 128
#define H_ 512
#define HO1 16777216ull
#define CO1 16809984ull
#define HO2 16842752ull
#define CO2 16875520ull

typedef __bf16 bf16_t;
typedef __attribute__((ext_vector_type(8))) __bf16 bf16x8;
typedef __attribute__((ext_vector_type(4))) float f32x4;
typedef __attribute__((ext_vector_type(8))) unsigned short u16x8;

// ---- workspace layout (bytes) ----
#define OFF_ARR   0ull        // arrival flags: [4 groups][64 WGs] u32
#define OFF_BC    1024ull     // broadcast flags: group g at +g*128
#define OFF_PG    2048ull     // prev_gen0 bf16 [64][128]
#define OFF_H1    18432ull    // h1 double buffer bf16 [2][64][512]
#define OFF_H2    149504ull   // h2 double buffer bf16 [2][64][512]
#define OFF_OUT   280576ull   // fc1 'out' bf16 [64][512]
#define OFF_B1P   346112ull   // fused bias1' fp32 [512]
#define OFF_WF    348160ull   // Wfused fp32 [512][512]
#define OFF_FRAG  1396736ull  // fragment heap (9984 frags x 1KiB)
// frag region bases (units of 1 frag = 64 lanes * 16B = 1KiB)
#define FR_S2   0
#define FR_S3   4096
#define FR_S1   8192
#define FR_S1T0 9472
#define FR_TOTAL 9984

__device__ __forceinline__ float sigm(float x) { return 1.f / (1.f + __expf(-x)); }
__device__ __forceinline__ float tanh_(float x) { return 2.f / (1.f + __expf(-2.f * x)) - 1.f; }

struct U128 { unsigned long long a, b; };

// cache-bypassing (fabric-coherent) 16B slab load: two 8B relaxed agent atomics.
// No buffer_inv/wbl2 — relaxed agent atomics lower to global_load sc0 sc1.
__device__ __forceinline__ bf16x8 ld_slab(const bf16_t* p) {
    unsigned long long* q = (unsigned long long*)p;
    U128 u;
    u.a = __hip_atomic_load(q, __ATOMIC_RELAXED, __HIP_MEMORY_SCOPE_AGENT);
    u.b = __hip_atomic_load(q + 1, __ATOMIC_RELAXED, __HIP_MEMORY_SCOPE_AGENT);
    return __builtin_bit_cast(bf16x8, u);
}

__device__ __forceinline__ void st_bf16(bf16_t* p, float v) {
    bf16_t b = (bf16_t)v;
    __hip_atomic_store((unsigned short*)p, __builtin_bit_cast(unsigned short, b),
                       __ATOMIC_RELAXED, __HIP_MEMORY_SCOPE_AGENT);
}

// ---------------- prep: init flags + small buffers ----------------
__global__ void k_init(const float* __restrict__ pg0, const float* __restrict__ h1i,
                       const float* __restrict__ h2i, uint8_t* __restrict__ ws) {
    int idx = blockIdx.x * 256 + threadIdx.x;
    if (idx < 384) ((unsigned int*)ws)[idx] = 0u;  // arrivals[256] + bcast region
    if (idx < B_ * F_) ((bf16_t*)(ws + OFF_PG))[idx] = (bf16_t)pg0[idx];
    if (idx < B_ * H_) {
        ((bf16_t*)(ws + OFF_H1))[B_ * H_ + idx] = (bf16_t)h1i[idx];  // buffer 1 = "t=-1"
        ((bf16_t*)(ws + OFF_H2))[B_ * H_ + idx] = (bf16_t)h2i[idx];
    }
}

// ---------------- prep: Wfused = W_fc1[:,128:256] @ W_fc2  (and bias1') ----------------
__global__ void k_fuse(const float* __restrict__ Wfc1, const float* __restrict__ bfc1,
                       const float* __restrict__ Wfc2, const float* __restrict__ bfc2,
                       uint8_t* __restrict__ ws) {
    int o = blockIdx.x;      // 0..511
    int t = threadIdx.x;     // 0..127
    __shared__ float wrow[128];
    wrow[t] = Wfc1[o * 256 + 128 + t];
    __syncthreads();
    float* WF = (float*)(ws + OFF_WF);
    f32x4 s = {0.f, 0.f, 0.f, 0.f};
    for (int m = 0; m < 128; ++m) {
        f32x4 b = *(const f32x4*)(Wfc2 + m * 512 + t * 4);
        float w = wrow[m];
        s[0] += w * b[0]; s[1] += w * b[1]; s[2] += w * b[2]; s[3] += w * b[3];
    }
    *(f32x4*)(WF + o * 512 + t * 4) = s;
    if (t == 0) {
        float sb = bfc1[o];
        for (int m = 0; m < 128; ++m) sb += wrow[m] * bfc2[m];
        ((float*)(ws + OFF_B1P))[o] = sb;
    }
}

// ---------------- prep: build MFMA B-fragments for all stages ----------------
__global__ void k_frags(const float* __restrict__ Wfc1, const float* __restrict__ Wih1,
                        const float* __restrict__ Whh1, const float* __restrict__ Wih2,
                        const float* __restrict__ Whh2, const float* __restrict__ Wfc2,
                        uint8_t* __restrict__ ws) {
    int gid = blockIdx.x * 256 + threadIdx.x;  // exactly FR_TOTAL*64 threads
    int fid = gid >> 6;
    int lane = gid & 63;
    int n16 = lane & 15, quad = lane >> 4;
    const float* WF = (const float*)(ws + OFF_WF);
    u16x8 pk;
#pragma unroll
    for (int j = 0; j < 8; ++j) {
        float v = 0.f;
        if (fid < 4096) {  // stage2 (LSTM1): in=[out|h1] K=1024, 32 gate-cols per WG
            int tl = fid & 1, ki = (fid >> 1) & 7, wv = (fid >> 4) & 3, wg = fid >> 6;
            int n32 = tl * 16 + n16; int j8 = n32 & 7; int gate = n32 >> 3;
            int R = gate * 512 + wg * 8 + j8;
            int k = wv * 256 + ki * 32 + quad * 8 + j;
            v = (k < 512) ? Wih1[R * 512 + k] : Whh1[R * 512 + k - 512];
        } else if (fid < 8192) {  // stage3 (LSTM2): in=[h1n|h2]
            int f2 = fid - 4096;
            int tl = f2 & 1, ki = (f2 >> 1) & 7, wv = (f2 >> 4) & 3, wg = f2 >> 6;
            int n32 = tl * 16 + n16; int j8 = n32 & 7; int gate = n32 >> 3;
            int R = gate * 512 + wg * 8 + j8;
            int k = wv * 256 + ki * 32 + quad * 8 + j;
            v = (k < 512) ? Wih2[R * 512 + k] : Whh2[R * 512 + k - 512];
        } else if (fid < 9472) {  // stage1 fused (t>=1): in=[x|h2p] K=640, cols=[out(8)|gen(2)|pad]
            int f2 = fid - 8192;
            int ki = f2 % 5; int wv = (f2 / 5) & 3; int wg = f2 / 20;
            int k = wv * 160 + ki * 32 + quad * 8 + j;
            if (n16 < 8) {
                int o = wg * 8 + n16;
                v = (k < 128) ? Wfc1[o * 256 + k] : WF[o * 512 + (k - 128)];
            } else if (n16 < 10) {
                int m = wg * 2 + (n16 - 8);
                v = (k < 128) ? 0.f : Wfc2[m * 512 + (k - 128)];
            }
        } else {  // stage1 at t==0: in=[x0|prev_gen0] K=256, W_fc1 direct
            int f2 = fid - 9472;
            int ki = f2 & 1; int wv = (f2 >> 1) & 3; int wg = f2 >> 3;
            int k = wv * 64 + ki * 32 + quad * 8 + j;
            if (n16 < 8) v = Wfc1[(wg * 8 + n16) * 256 + k];
        }
        bf16_t bb = (bf16_t)v;
        pk[j] = __builtin_bit_cast(unsigned short, bb);
    }
    *((u16x8*)(ws + OFF_FRAG) + (size_t)fid * 64 + lane) = pk;
}

// ---------------- flag-broadcast group barrier (64 WGs, no cache fences) ----------------
// Data ordering: each wave drains its own stores (vmcnt 0) -> __syncthreads ->
// tid0 stores monotonic arrival flag (relaxed agent = fabric-coherent). Master
// WG's wave0 polls all 64 arrival flags (one lane each), then lane0 stores the
// broadcast flag; everyone polls broadcast. All flag/data traffic bypasses the
// non-coherent L1/L2 via sc0 sc1 — no buffer_wbl2 / buffer_inv anywhere.
__device__ __forceinline__ void gbar(unsigned int* arr, unsigned int* bc, int wg,
                                     int tid, int lane, unsigned int tgt) {
    asm volatile("s_waitcnt vmcnt(0)" ::: "memory");
    __syncthreads();
    if (tid == 0)
        __hip_atomic_store(arr + wg, tgt, __ATOMIC_RELAXED, __HIP_MEMORY_SCOPE_AGENT);
    if (wg == 0 && tid < 64) {
        while (!__all((int)(__hip_atomic_load(arr + lane, __ATOMIC_RELAXED,
                                              __HIP_MEMORY_SCOPE_AGENT) >= tgt))) {}
        if (lane == 0)
            __hip_atomic_store(bc, tgt, __ATOMIC_RELAXED, __HIP_MEMORY_SCOPE_AGENT);
    }
    if (tid == 0)
        while (__hip_atomic_load(bc, __ATOMIC_RELAXED, __HIP_MEMORY_SCOPE_AGENT) < tgt) {}
    __syncthreads();
}

// ---------------- persistent recurrence kernel ----------------
// grid = 256 WGs: blockIdx = g*64 + wg  (g: batch-group 0..3 -> rows g*16..g*16+15;
// wg: column-group 0..63). 256 threads = 4 waves; weights live in VGPRs/AGPRs.
__launch_bounds__(256, 1)
__global__ void k_rnn(const float* __restrict__ x, const float* __restrict__ c1i,
                      const float* __restrict__ c2i, const float* __restrict__ bfc1,
                      const float* __restrict__ b1, const float* __restrict__ b2g,
                      const float* __restrict__ bfc2, uint8_t* __restrict__ ws,
                      float* __restrict__ out) {
    const int wg = blockIdx.x & 63;
    const int g = blockIdx.x >> 6;
    const int tid = threadIdx.x;
    const int wave = tid >> 6, lane = tid & 63;
    const int quad = lane >> 4, row16 = lane & 15;
    const int b_ = g * 16 + row16;

    bf16_t* pg = (bf16_t*)(ws + OFF_PG);
    bf16_t* h1b = (bf16_t*)(ws + OFF_H1);
    bf16_t* h2b = (bf16_t*)(ws + OFF_H2);
    bf16_t* outb = (bf16_t*)(ws + OFF_OUT);
    const float* b1p = (const float*)(ws + OFF_B1P);
    unsigned int* arr = (unsigned int*)(ws + OFF_ARR) + g * 64;
    unsigned int* bc = (unsigned int*)(ws + OFF_BC + (size_t)g * 128);
    const u16x8* heap = (const u16x8*)(ws + OFF_FRAG);

    // ---- load all weight fragments into registers (stationary for all 2048 steps) ----
    bf16x8 fr2[16], fr3[16], fr1[5], fr10[2];
    const int wslot = wg * 4 + wave;
#pragma unroll
    for (int f = 0; f < 16; ++f)
        fr2[f] = __builtin_bit_cast(bf16x8, heap[(size_t)(FR_S2 + wslot * 16 + f) * 64 + lane]);
#pragma unroll
    for (int f = 0; f < 16; ++f)
        fr3[f] = __builtin_bit_cast(bf16x8, heap[(size_t)(FR_S3 + wslot * 16 + f) * 64 + lane]);
#pragma unroll
    for (int f = 0; f < 5; ++f)
        fr1[f] = __builtin_bit_cast(bf16x8, heap[(size_t)(FR_S1 + wslot * 5 + f) * 64 + lane]);
#pragma unroll
    for (int f = 0; f < 2; ++f)
        fr10[f] = __builtin_bit_cast(bf16x8, heap[(size_t)(FR_S1T0 + wslot * 2 + f) * 64 + lane]);

    __shared__ float red[4][2][16][16];
    __shared__ float gbuf[16][33];       // +1 pad: kills 8-way bank conflicts
    __shared__ float cb1[16][9], cb2[16][9];

    // per-thread biases for the reduction step: (rrow, rc) covers the 16x16 D-tile
    const int rrow = tid >> 4, rc = tid & 15;
    const float bias2_a = b1[(rc >> 3) * 512 + wg * 8 + (rc & 7)];
    const float bias2_b = b1[(2 + (rc >> 3)) * 512 + wg * 8 + (rc & 7)];
    const float bias3_a = b2g[(rc >> 3) * 512 + wg * 8 + (rc & 7)];
    const float bias3_b = b2g[(2 + (rc >> 3)) * 512 + wg * 8 + (rc & 7)];
    const float bias1 = (rc < 8) ? b1p[wg * 8 + rc] : ((rc < 10) ? bfc2[wg * 2 + rc - 8] : 0.f);
    const float bias1t0 = (rc < 8) ? bfc1[wg * 8 + rc] : 0.f;

    if (tid < 128) {  // cell state stays local (fp32) for the whole sequence
        int r = tid >> 3, j = tid & 7;
        cb1[r][j] = c1i[(g * 16 + r) * 512 + wg * 8 + j];
        cb2[r][j] = c2i[(g * 16 + r) * 512 + wg * 8 + j];
    }
    __syncthreads();

    unsigned int bt = 0;

#pragma clang loop unroll(disable)
    for (int t = 0; t <= S_; ++t) {
        const int cbuf = t & 1, pbuf = cbuf ^ 1;

        // ============ P1: out = relu([x_t | h2p] @ W1') ; gen(t-1) = extra cols ============
        {
            f32x4 acc = {0.f, 0.f, 0.f, 0.f};
            if (t == 0) {
#pragma unroll
                for (int ki = 0; ki < 2; ++ki) {
                    int k = wave * 64 + ki * 32 + quad * 8;
                    bf16x8 a;
                    if (k < 128) {
                        const float* xp = x + ((size_t)b_ * S_) * F_ + k;
                        f32x4 x0 = *(const f32x4*)xp, x1 = *(const f32x4*)(xp + 4);
#pragma unroll
                        for (int i = 0; i < 4; ++i) { a[i] = (bf16_t)x0[i]; a[4 + i] = (bf16_t)x1[i]; }
                    } else {
                        a = *(const bf16x8*)(pg + (size_t)b_ * 128 + (k - 128));
                    }
                    acc = __builtin_amdgcn_mfma_f32_16x16x32_bf16(a, fr10[ki], acc, 0, 0, 0);
                }
            } else {
                const int tx = (t < S_) ? t : (S_ - 1);  // t==S_: x part hits zero weights
                const bf16_t* h2p = h2b + (size_t)pbuf * (B_ * H_);
#pragma unroll
                for (int ki = 0; ki < 5; ++ki) {
                    int k = wave * 160 + ki * 32 + quad * 8;
                    bf16x8 a;
                    if (k < 128) {
                        const float* xp = x + ((size_t)b_ * S_ + tx) * F_ + k;
                        f32x4 x0 = *(const f32x4*)xp, x1 = *(const f32x4*)(xp + 4);
#pragma unroll
                        for (int i = 0; i < 4; ++i) { a[i] = (bf16_t)x0[i]; a[4 + i] = (bf16_t)x1[i]; }
                    } else {
                        a = ld_slab(h2p + (size_t)b_ * H_ + (k - 128));
                    }
                    acc = __builtin_amdgcn_mfma_f32_16x16x32_bf16(a, fr1[ki], acc, 0, 0, 0);
                }
            }
#pragma unroll
            for (int i = 0; i < 4; ++i) red[wave][0][quad * 4 + i][row16] = acc[i];
            __syncthreads();
            float v = red[0][0][rrow][rc] + red[1][0][rrow][rc] + red[2][0][rrow][rc] +
                      red[3][0][rrow][rc];
            if (t == 0) {
                if (rc < 8) {
                    v = fmaxf(v + bias1t0, 0.f);
                    st_bf16(&outb[(size_t)(g * 16 + rrow) * H_ + wg * 8 + rc], v);
                }
            } else if (rc < 8) {
                if (t < S_) {
                    v = fmaxf(v + bias1, 0.f);
                    st_bf16(&outb[(size_t)(g * 16 + rrow) * H_ + wg * 8 + rc], v);
                }
            } else if (rc < 10) {  // gen(t-1) -> d_out (fp32)
                out[(size_t)(g * 16 + rrow) * (S_ * F_) + (size_t)(t - 1) * F_ + wg * 2 + (rc - 8)] =
                    v + bias1;
            }
        }
        if (t == S_) break;  // last gen written; done
        gbar(arr, bc, wg, tid, lane, ++bt);

        // ============ P2: LSTM1 gates = [out | h1(t-1)] @ W ; update c1, h1n ============
        {
            const bf16_t* h1p = h1b + (size_t)pbuf * (B_ * H_);
            const bf16_t* asrc = (wave < 2) ? (outb + (size_t)b_ * H_ + wave * 256)
                                            : (h1p + (size_t)b_ * H_ + (wave - 2) * 256);
            f32x4 acc0 = {0.f, 0.f, 0.f, 0.f}, acc1 = {0.f, 0.f, 0.f, 0.f};
#pragma unroll
            for (int ki = 0; ki < 8; ++ki) {
                bf16x8 a = ld_slab(asrc + quad * 8 + ki * 32);
                acc0 = __builtin_amdgcn_mfma_f32_16x16x32_bf16(a, fr2[ki * 2 + 0], acc0, 0, 0, 0);
                acc1 = __builtin_amdgcn_mfma_f32_16x16x32_bf16(a, fr2[ki * 2 + 1], acc1, 0, 0, 0);
            }
#pragma unroll
            for (int i = 0; i < 4; ++i) {
                red[wave][0][quad * 4 + i][row16] = acc0[i];
                red[wave][1][quad * 4 + i][row16] = acc1[i];
            }
            __syncthreads();
            float v0 = red[0][0][rrow][rc] + red[1][0][rrow][rc] + red[2][0][rrow][rc] +
                       red[3][0][rrow][rc] + bias2_a;
            float v1 = red[0][1][rrow][rc] + red[1][1][rrow][rc] + red[2][1][rrow][rc] +
                       red[3][1][rrow][rc] + bias2_b;
            gbuf[rrow][rc] = v0;       // cols 0..15: i,f
            gbuf[rrow][rc + 16] = v1;  // cols 16..31: g,o
            __syncthreads();
            if (tid < 128) {
                int r = tid >> 3, j = tid & 7;
                float gi = gbuf[r][j], gf = gbuf[r][8 + j], gg = gbuf[r][16 + j], go = gbuf[r][24 + j];
                float cn = sigm(gf) * cb1[r][j] + sigm(gi) * tanh_(gg);
                cb1[r][j] = cn;
                float h = sigm(go) * tanh_(cn);
                st_bf16(&h1b[(size_t)cbuf * (B_ * H_) + (size_t)(g * 16 + r) * H_ + wg * 8 + j], h);
                if (t == S_ - 1) {
                    out[HO1 + (size_t)(g * 16 + r) * H_ + wg * 8 + j] = h;
                    out[CO1 + (size_t)(g * 16 + r) * H_ + wg * 8 + j] = cn;
                }
            }
        }
        gbar(arr, bc, wg, tid, lane, ++bt);

        // ============ P3: LSTM2 gates = [h1n | h2(t-1)] @ W ; update c2, h2n ============
        {
            const bf16_t* h1c = h1b + (size_t)cbuf * (B_ * H_);
            const bf16_t* h2p = h2b + (size_t)pbuf * (B_ * H_);
            const bf16_t* asrc = (wave < 2) ? (h1c + (size_t)b_ * H_ + wave * 256)
                                            : (h2p + (size_t)b_ * H_ + (wave - 2) * 256);
            f32x4 acc0 = {0.f, 0.f, 0.f, 0.f}, acc1 = {0.f, 0.f, 0.f, 0.f};
#pragma unroll
            for (int ki = 0; ki < 8; ++ki) {
                bf16x8 a = ld_slab(asrc + quad * 8 + ki * 32);
                acc0 = __builtin_amdgcn_mfma_f32_16x16x32_bf16(a, fr3[ki * 2 + 0], acc0, 0, 0, 0);
                acc1 = __builtin_amdgcn_mfma_f32_16x16x32_bf16(a, fr3[ki * 2 + 1], acc1, 0, 0, 0);
            }
#pragma unroll
            for (int i = 0; i < 4; ++i) {
                red[wave][0][quad * 4 + i][row16] = acc0[i];
                red[wave][1][quad * 4 + i][row16] = acc1[i];
            }
            __syncthreads();
            float v0 = red[0][0][rrow][rc] + red[1][0][rrow][rc] + red[2][0][rrow][rc] +
                       red[3][0][rrow][rc] + bias3_a;
            float v1 = red[0][1][rrow][rc] + red[1][1][rrow][rc] + red[2][1][rrow][rc] +
                       red[3][1][rrow][rc] + bias3_b;
            gbuf[rrow][rc] = v0;
            gbuf[rrow][rc + 16] = v1;
            __syncthreads();
            if (tid < 128) {
                int r = tid >> 3, j = tid & 7;
                float gi = gbuf[r][j], gf = gbuf[r][8 + j], gg = gbuf[r][16 + j], go = gbuf[r][24 + j];
                float cn = sigm(gf) * cb2[r][j] + sigm(gi) * tanh_(gg);
                cb2[r][j] = cn;
                float h = sigm(go) * tanh_(cn);
                st_bf16(&h2b[(size_t)cbuf * (B_ * H_) + (size_t)(g * 16 + r) * H_ + wg * 8 + j], h);
                if (t == S_ - 1) {
                    out[HO2 + (size_t)(g * 16 + r) * H_ + wg * 8 + j] = h;
                    out[CO2 + (size_t)(g * 16 + r) * H_ + wg * 8 + j] = cn;
                }
            }
        }
        gbar(arr, bc, wg, tid, lane, ++bt);
    }
}

extern "C" void kernel_launch(void* const* d_in, const int* in_sizes, int n_in, void* d_out,
                              int out_size, void* d_ws, size_t ws_size, hipStream_t stream) {
    const float* x = (const float*)d_in[0];
    const float* pg0 = (const float*)d_in[1];
    const float* h1i = (const float*)d_in[2];
    const float* c1i = (const float*)d_in[3];
    const float* h2i = (const float*)d_in[4];
    const float* c2i = (const float*)d_in[5];
    const float* Wfc1 = (const float*)d_in[6];
    const float* bfc1 = (const float*)d_in[7];
    const float* Wih1 = (const float*)d_in[8];
    const float* Whh1 = (const float*)d_in[9];
    const float* b1 = (const float*)d_in[10];
    const float* Wih2 = (const float*)d_in[11];
    const float* Whh2 = (const float*)d_in[12];
    const float* b2g = (const float*)d_in[13];
    const float* Wfc2 = (const float*)d_in[14];
    const float* bfc2 = (const float*)d_in[15];
    uint8_t* ws = (uint8_t*)d_ws;
    float* out = (float*)d_out;

    k_init<<<dim3(128), dim3(256), 0, stream>>>(pg0, h1i, h2i, ws);
    k_fuse<<<dim3(512), dim3(128), 0, stream>>>(Wfc1, bfc1, Wfc2, bfc2, ws);
    k_frags<<<dim3(2496), dim3(256), 0, stream>>>(Wfc1, Wih1, Whh1, Wih2, Whh2, Wfc2, ws);
    k_rnn<<<dim3(256), dim3(256), 0, stream>>>(x, c1i, c2i, bfc1, b1, b2g, bfc2, ws, out);
}

// Round 3
// 23912.579 us; speedup vs baseline: 6.1918x; 1.2010x over previous
//
#include <hip/hip_runtime.h>
#include <cstdint>
#include <cstddef>

// Problem constants
#define B_ 64
#define S_ 2048
#define F_ 128
#define H_ 512
#define HO1 16777216ull
#define CO1 16809984ull
#define HO2 16842752ull
#define CO2 16875520ull

typedef __bf16 bf16_t;
typedef __attribute__((ext_vector_type(8))) __bf16 bf16x8;
typedef __attribute__((ext_vector_type(4))) float f32x4;
typedef __attribute__((ext_vector_type(8))) unsigned short u16x8;

// ---- workspace layout (bytes) ----
#define OFF_ARR   0ull        // arrival flags: [4 groups][64 WGs] u32
#define OFF_PG    2048ull     // prev_gen0 bf16 [64][128]
#define OFF_H1    18432ull    // h1 double buffer bf16 [2][64][512]
#define OFF_H2    149504ull   // h2 double buffer bf16 [2][64][512]
#define OFF_OUT   280576ull   // fc1 'out' bf16 [64][512]
#define OFF_B1P   346112ull   // fused bias1' fp32 [512]
#define OFF_WF    348160ull   // Wfused fp32 [512][512]
#define OFF_FRAG  1396736ull  // fragment heap (9984 frags x 1KiB)
// frag region bases (units of 1 frag = 64 lanes * 16B = 1KiB)
#define FR_S2   0
#define FR_S3   4096
#define FR_S1   8192
#define FR_S1T0 9472
#define FR_TOTAL 9984

__device__ __forceinline__ float sigm(float x) { return 1.f / (1.f + __expf(-x)); }
__device__ __forceinline__ float tanh_(float x) { return 2.f / (1.f + __expf(-2.f * x)) - 1.f; }

struct U128 { unsigned long long a, b; };

// cache-bypassing (fabric-coherent) 16B slab load: two 8B relaxed agent atomics.
// No buffer_inv/wbl2 — relaxed agent atomics lower to global_load sc0 sc1.
__device__ __forceinline__ bf16x8 ld_slab(const bf16_t* p) {
    unsigned long long* q = (unsigned long long*)p;
    U128 u;
    u.a = __hip_atomic_load(q, __ATOMIC_RELAXED, __HIP_MEMORY_SCOPE_AGENT);
    u.b = __hip_atomic_load(q + 1, __ATOMIC_RELAXED, __HIP_MEMORY_SCOPE_AGENT);
    return __builtin_bit_cast(bf16x8, u);
}

__device__ __forceinline__ void st_bf16(bf16_t* p, float v) {
    bf16_t b = (bf16_t)v;
    __hip_atomic_store((unsigned short*)p, __builtin_bit_cast(unsigned short, b),
                       __ATOMIC_RELAXED, __HIP_MEMORY_SCOPE_AGENT);
}

// ---------------- prep: init flags + small buffers ----------------
__global__ void k_init(const float* __restrict__ pg0, const float* __restrict__ h1i,
                       const float* __restrict__ h2i, uint8_t* __restrict__ ws) {
    int idx = blockIdx.x * 256 + threadIdx.x;
    if (idx < 512) ((unsigned int*)ws)[idx] = 0u;  // arrival flags
    if (idx < B_ * F_) ((bf16_t*)(ws + OFF_PG))[idx] = (bf16_t)pg0[idx];
    if (idx < B_ * H_) {
        ((bf16_t*)(ws + OFF_H1))[B_ * H_ + idx] = (bf16_t)h1i[idx];  // buffer 1 = "t=-1"
        ((bf16_t*)(ws + OFF_H2))[B_ * H_ + idx] = (bf16_t)h2i[idx];
    }
}

// ---------------- prep: Wfused = W_fc1[:,128:256] @ W_fc2  (and bias1') ----------------
__global__ void k_fuse(const float* __restrict__ Wfc1, const float* __restrict__ bfc1,
                       const float* __restrict__ Wfc2, const float* __restrict__ bfc2,
                       uint8_t* __restrict__ ws) {
    int o = blockIdx.x;      // 0..511
    int t = threadIdx.x;     // 0..127
    __shared__ float wrow[128];
    wrow[t] = Wfc1[o * 256 + 128 + t];
    __syncthreads();
    float* WF = (float*)(ws + OFF_WF);
    f32x4 s = {0.f, 0.f, 0.f, 0.f};
    for (int m = 0; m < 128; ++m) {
        f32x4 b = *(const f32x4*)(Wfc2 + m * 512 + t * 4);
        float w = wrow[m];
        s[0] += w * b[0]; s[1] += w * b[1]; s[2] += w * b[2]; s[3] += w * b[3];
    }
    *(f32x4*)(WF + o * 512 + t * 4) = s;
    if (t == 0) {
        float sb = bfc1[o];
        for (int m = 0; m < 128; ++m) sb += wrow[m] * bfc2[m];
        ((float*)(ws + OFF_B1P))[o] = sb;
    }
}

// ---------------- prep: build MFMA B-fragments for all stages ----------------
__global__ void k_frags(const float* __restrict__ Wfc1, const float* __restrict__ Wih1,
                        const float* __restrict__ Whh1, const float* __restrict__ Wih2,
                        const float* __restrict__ Whh2, const float* __restrict__ Wfc2,
                        uint8_t* __restrict__ ws) {
    int gid = blockIdx.x * 256 + threadIdx.x;  // exactly FR_TOTAL*64 threads
    int fid = gid >> 6;
    int lane = gid & 63;
    int n16 = lane & 15, quad = lane >> 4;
    const float* WF = (const float*)(ws + OFF_WF);
    u16x8 pk;
#pragma unroll
    for (int j = 0; j < 8; ++j) {
        float v = 0.f;
        if (fid < 4096) {  // stage2 (LSTM1): in=[out|h1] K=1024, 32 gate-cols per WG
            int tl = fid & 1, ki = (fid >> 1) & 7, wv = (fid >> 4) & 3, wg = fid >> 6;
            int n32 = tl * 16 + n16; int j8 = n32 & 7; int gate = n32 >> 3;
            int R = gate * 512 + wg * 8 + j8;
            int k = wv * 256 + ki * 32 + quad * 8 + j;
            v = (k < 512) ? Wih1[R * 512 + k] : Whh1[R * 512 + k - 512];
        } else if (fid < 8192) {  // stage3 (LSTM2): in=[h1n|h2]
            int f2 = fid - 4096;
            int tl = f2 & 1, ki = (f2 >> 1) & 7, wv = (f2 >> 4) & 3, wg = f2 >> 6;
            int n32 = tl * 16 + n16; int j8 = n32 & 7; int gate = n32 >> 3;
            int R = gate * 512 + wg * 8 + j8;
            int k = wv * 256 + ki * 32 + quad * 8 + j;
            v = (k < 512) ? Wih2[R * 512 + k] : Whh2[R * 512 + k - 512];
        } else if (fid < 9472) {  // stage1 fused (t>=1): in=[x|h2p] K=640, cols=[out(8)|gen(2)|pad]
            int f2 = fid - 8192;
            int ki = f2 % 5; int wv = (f2 / 5) & 3; int wg = f2 / 20;
            int k = wv * 160 + ki * 32 + quad * 8 + j;
            if (n16 < 8) {
                int o = wg * 8 + n16;
                v = (k < 128) ? Wfc1[o * 256 + k] : WF[o * 512 + (k - 128)];
            } else if (n16 < 10) {
                int m = wg * 2 + (n16 - 8);
                v = (k < 128) ? 0.f : Wfc2[m * 512 + (k - 128)];
            }
        } else {  // stage1 at t==0: in=[x0|prev_gen0] K=256, W_fc1 direct
            int f2 = fid - 9472;
            int ki = f2 & 1; int wv = (f2 >> 1) & 3; int wg = f2 >> 3;
            int k = wv * 64 + ki * 32 + quad * 8 + j;
            if (n16 < 8) v = Wfc1[(wg * 8 + n16) * 256 + k];
        }
        bf16_t bb = (bf16_t)v;
        pk[j] = __builtin_bit_cast(unsigned short, bb);
    }
    *((u16x8*)(ws + OFF_FRAG) + (size_t)fid * 64 + lane) = pk;
}

// ---------------- distributed flag barrier (64 WGs, single fabric round) ----------------
// arrive: drain own data stores (vmcnt 0, all waves) -> syncthreads -> tid0 stores
// monotonic epoch to its own flag word (relaxed agent = fabric-coherent, no L2 fences).
// wait: wave0 polls all 64 flags (one per lane) with __all, then syncthreads releases
// the WG. Between arrive and wait the caller inserts off-critical-path stores and
// register prefetch of stale operands — they fly while we poll.
__device__ __forceinline__ void bar_arrive(unsigned int* arr, int wg, int tid,
                                           unsigned int tgt) {
    asm volatile("s_waitcnt vmcnt(0)" ::: "memory");
    __syncthreads();
    if (tid == 0)
        __hip_atomic_store(arr + wg, tgt, __ATOMIC_RELAXED, __HIP_MEMORY_SCOPE_AGENT);
}
__device__ __forceinline__ void bar_wait(const unsigned int* arr, int tid, int lane,
                                         unsigned int tgt) {
    if (tid < 64) {
        while (!__all((int)(__hip_atomic_load(arr + lane, __ATOMIC_RELAXED,
                                              __HIP_MEMORY_SCOPE_AGENT) >= tgt))) {}
    }
    __syncthreads();
}

// ---------------- persistent recurrence kernel ----------------
// grid = 256 WGs: blockIdx = g*64 + wg  (g: batch-group 0..3 -> rows g*16..g*16+15;
// wg: column-group 0..63). 256 threads = 4 waves; weights live in VGPRs/AGPRs.
__launch_bounds__(256, 1)
__global__ void k_rnn(const float* __restrict__ x, const float* __restrict__ c1i,
                      const float* __restrict__ c2i, const float* __restrict__ bfc1,
                      const float* __restrict__ b1, const float* __restrict__ b2g,
                      const float* __restrict__ bfc2, uint8_t* __restrict__ ws,
                      float* __restrict__ out) {
    const int wg = blockIdx.x & 63;
    const int g = blockIdx.x >> 6;
    const int tid = threadIdx.x;
    const int wave = tid >> 6, lane = tid & 63;
    const int quad = lane >> 4, row16 = lane & 15;
    const int b_ = g * 16 + row16;

    bf16_t* pg = (bf16_t*)(ws + OFF_PG);
    bf16_t* h1b = (bf16_t*)(ws + OFF_H1);
    bf16_t* h2b = (bf16_t*)(ws + OFF_H2);
    bf16_t* outb = (bf16_t*)(ws + OFF_OUT);
    const float* b1p = (const float*)(ws + OFF_B1P);
    unsigned int* arr = (unsigned int*)(ws + OFF_ARR) + g * 64;
    const u16x8* heap = (const u16x8*)(ws + OFF_FRAG);

    // ---- load all weight fragments into registers (stationary for all 2048 steps) ----
    bf16x8 fr2[16], fr3[16], fr1[5], fr10[2];
    const int wslot = wg * 4 + wave;
#pragma unroll
    for (int f = 0; f < 16; ++f)
        fr2[f] = __builtin_bit_cast(bf16x8, heap[(size_t)(FR_S2 + wslot * 16 + f) * 64 + lane]);
#pragma unroll
    for (int f = 0; f < 16; ++f)
        fr3[f] = __builtin_bit_cast(bf16x8, heap[(size_t)(FR_S3 + wslot * 16 + f) * 64 + lane]);
#pragma unroll
    for (int f = 0; f < 5; ++f)
        fr1[f] = __builtin_bit_cast(bf16x8, heap[(size_t)(FR_S1 + wslot * 5 + f) * 64 + lane]);
#pragma unroll
    for (int f = 0; f < 2; ++f)
        fr10[f] = __builtin_bit_cast(bf16x8, heap[(size_t)(FR_S1T0 + wslot * 2 + f) * 64 + lane]);

    __shared__ float red[4][2][16][17];  // +1 pad: breaks 4-way quad aliasing
    __shared__ float gbuf[16][33];
    __shared__ float cb1[16][9], cb2[16][9];

    // per-thread biases for the reduction step: (rrow, rc) covers the 16x16 D-tile
    const int rrow = tid >> 4, rc = tid & 15;
    const float bias2_a = b1[(rc >> 3) * 512 + wg * 8 + (rc & 7)];
    const float bias2_b = b1[(2 + (rc >> 3)) * 512 + wg * 8 + (rc & 7)];
    const float bias3_a = b2g[(rc >> 3) * 512 + wg * 8 + (rc & 7)];
    const float bias3_b = b2g[(2 + (rc >> 3)) * 512 + wg * 8 + (rc & 7)];
    const float bias1 = (rc < 8) ? b1p[wg * 8 + rc] : ((rc < 10) ? bfc2[wg * 2 + rc - 8] : 0.f);
    const float bias1t0 = (rc < 8) ? bfc1[wg * 8 + rc] : 0.f;

    if (tid < 128) {  // cell state stays local (fp32) for the whole sequence
        int r = tid >> 3, j = tid & 7;
        cb1[r][j] = c1i[(g * 16 + r) * 512 + wg * 8 + j];
        cb2[r][j] = c2i[(g * 16 + r) * 512 + wg * 8 + j];
    }
    __syncthreads();

    unsigned int bt = 0;
    bf16x8 xpre[4];  // x(t) bf16 prefetch, wave0 only (cols 32*ki + quad*8 .. +7)

#pragma clang loop unroll(disable)
    for (int t = 0; t <= S_; ++t) {
        const int cbuf = t & 1, pbuf = cbuf ^ 1;
        bf16x8 pre2[8], pre3[8];  // stale-operand prefetch (waves 2-3)

        // ============ P1: out = relu([x_t | h2p] @ W1') ; gen(t-1) = extra cols ============
        if (t > 0) bar_wait(arr, tid, lane, bt);  // P3(t-1) done -> h2(t-1) visible
        {
            f32x4 acc = {0.f, 0.f, 0.f, 0.f};
            if (t == 0) {
#pragma unroll
                for (int ki = 0; ki < 2; ++ki) {
                    int k = wave * 64 + ki * 32 + quad * 8;
                    bf16x8 a;
                    if (k < 128) {
                        const float* xp = x + ((size_t)b_ * S_) * F_ + k;
                        f32x4 x0 = *(const f32x4*)xp, x1 = *(const f32x4*)(xp + 4);
#pragma unroll
                        for (int i = 0; i < 4; ++i) { a[i] = (bf16_t)x0[i]; a[4 + i] = (bf16_t)x1[i]; }
                    } else {
                        a = *(const bf16x8*)(pg + (size_t)b_ * 128 + (k - 128));
                    }
                    acc = __builtin_amdgcn_mfma_f32_16x16x32_bf16(a, fr10[ki], acc, 0, 0, 0);
                }
            } else {
                const bf16_t* h2p = h2b + (size_t)pbuf * (B_ * H_) + (size_t)b_ * H_;
#pragma unroll
                for (int ki = 0; ki < 5; ++ki) {
                    int k = wave * 160 + ki * 32 + quad * 8;
                    bf16x8 a;
                    if (wave == 0 && ki < 4) a = xpre[ki];  // prefetched last step
                    else a = ld_slab(h2p + (k - 128));
                    acc = __builtin_amdgcn_mfma_f32_16x16x32_bf16(a, fr1[ki], acc, 0, 0, 0);
                }
            }
#pragma unroll
            for (int i = 0; i < 4; ++i) red[wave][0][quad * 4 + i][row16] = acc[i];
            __syncthreads();
            float v = red[0][0][rrow][rc] + red[1][0][rrow][rc] + red[2][0][rrow][rc] +
                      red[3][0][rrow][rc];
            // fresh slab first (others wait on it), then arrive, then HBM gen store
            if (rc < 8 && t < S_) {
                float vv = fmaxf(v + (t == 0 ? bias1t0 : bias1), 0.f);
                st_bf16(&outb[(size_t)(g * 16 + rrow) * H_ + wg * 8 + rc], vv);
            }
            if (t < S_) bar_arrive(arr, wg, tid, ++bt);
            if (t > 0 && rc >= 8 && rc < 10) {  // gen(t-1) -> d_out (fp32), off critical path
                out[(size_t)(g * 16 + rrow) * (S_ * F_) + (size_t)(t - 1) * F_ + wg * 2 + (rc - 8)] =
                    v + bias1;
            }
        }
        if (t == S_) break;  // last gen written; done
        // prefetch h1(t-1) (stale, visible since P2(t-1)) while polling
        if (wave >= 2) {
            const bf16_t* h1p = h1b + (size_t)pbuf * (B_ * H_) + (size_t)b_ * H_ +
                                (wave - 2) * 256 + quad * 8;
#pragma unroll
            for (int ki = 0; ki < 8; ++ki) pre2[ki] = ld_slab(h1p + ki * 32);
        }
        bar_wait(arr, tid, lane, bt);

        // ============ P2: LSTM1 gates = [out | h1(t-1)] @ W ; update c1, h1n ============
        {
            f32x4 acc0 = {0.f, 0.f, 0.f, 0.f}, acc1 = {0.f, 0.f, 0.f, 0.f};
            if (wave < 2) {
                const bf16_t* asrc = outb + (size_t)b_ * H_ + wave * 256 + quad * 8;
#pragma unroll
                for (int ki = 0; ki < 8; ++ki) {
                    bf16x8 a = ld_slab(asrc + ki * 32);
                    acc0 = __builtin_amdgcn_mfma_f32_16x16x32_bf16(a, fr2[ki * 2 + 0], acc0, 0, 0, 0);
                    acc1 = __builtin_amdgcn_mfma_f32_16x16x32_bf16(a, fr2[ki * 2 + 1], acc1, 0, 0, 0);
                }
            } else {
#pragma unroll
                for (int ki = 0; ki < 8; ++ki) {
                    acc0 = __builtin_amdgcn_mfma_f32_16x16x32_bf16(pre2[ki], fr2[ki * 2 + 0], acc0, 0, 0, 0);
                    acc1 = __builtin_amdgcn_mfma_f32_16x16x32_bf16(pre2[ki], fr2[ki * 2 + 1], acc1, 0, 0, 0);
                }
            }
#pragma unroll
            for (int i = 0; i < 4; ++i) {
                red[wave][0][quad * 4 + i][row16] = acc0[i];
                red[wave][1][quad * 4 + i][row16] = acc1[i];
            }
            __syncthreads();
            float v0 = red[0][0][rrow][rc] + red[1][0][rrow][rc] + red[2][0][rrow][rc] +
                       red[3][0][rrow][rc] + bias2_a;
            float v1 = red[0][1][rrow][rc] + red[1][1][rrow][rc] + red[2][1][rrow][rc] +
                       red[3][1][rrow][rc] + bias2_b;
            gbuf[rrow][rc] = v0;       // cols 0..15: i,f
            gbuf[rrow][rc + 16] = v1;  // cols 16..31: g,o
            __syncthreads();
            if (tid < 128) {
                int r = tid >> 3, j = tid & 7;
                float gi = gbuf[r][j], gf = gbuf[r][8 + j], gg = gbuf[r][16 + j], go = gbuf[r][24 + j];
                float cn = sigm(gf) * cb1[r][j] + sigm(gi) * tanh_(gg);
                cb1[r][j] = cn;
                float h = sigm(go) * tanh_(cn);
                st_bf16(&h1b[(size_t)cbuf * (B_ * H_) + (size_t)(g * 16 + r) * H_ + wg * 8 + j], h);
                if (t == S_ - 1) {
                    out[HO1 + (size_t)(g * 16 + r) * H_ + wg * 8 + j] = h;
                    out[CO1 + (size_t)(g * 16 + r) * H_ + wg * 8 + j] = cn;
                }
            }
        }
        bar_arrive(arr, wg, tid, ++bt);
        // prefetch h2(t-1) (stale, visible since P3(t-1)) while polling
        if (wave >= 2) {
            const bf16_t* h2p = h2b + (size_t)pbuf * (B_ * H_) + (size_t)b_ * H_ +
                                (wave - 2) * 256 + quad * 8;
#pragma unroll
            for (int ki = 0; ki < 8; ++ki) pre3[ki] = ld_slab(h2p + ki * 32);
        }
        bar_wait(arr, tid, lane, bt);

        // ============ P3: LSTM2 gates = [h1n | h2(t-1)] @ W ; update c2, h2n ============
        {
            f32x4 acc0 = {0.f, 0.f, 0.f, 0.f}, acc1 = {0.f, 0.f, 0.f, 0.f};
            if (wave < 2) {
                const bf16_t* asrc = h1b + (size_t)cbuf * (B_ * H_) + (size_t)b_ * H_ +
                                     wave * 256 + quad * 8;
#pragma unroll
                for (int ki = 0; ki < 8; ++ki) {
                    bf16x8 a = ld_slab(asrc + ki * 32);
                    acc0 = __builtin_amdgcn_mfma_f32_16x16x32_bf16(a, fr3[ki * 2 + 0], acc0, 0, 0, 0);
                    acc1 = __builtin_amdgcn_mfma_f32_16x16x32_bf16(a, fr3[ki * 2 + 1], acc1, 0, 0, 0);
                }
            } else {
#pragma unroll
                for (int ki = 0; ki < 8; ++ki) {
                    acc0 = __builtin_amdgcn_mfma_f32_16x16x32_bf16(pre3[ki], fr3[ki * 2 + 0], acc0, 0, 0, 0);
                    acc1 = __builtin_amdgcn_mfma_f32_16x16x32_bf16(pre3[ki], fr3[ki * 2 + 1], acc1, 0, 0, 0);
                }
            }
#pragma unroll
            for (int i = 0; i < 4; ++i) {
                red[wave][0][quad * 4 + i][row16] = acc0[i];
                red[wave][1][quad * 4 + i][row16] = acc1[i];
            }
            __syncthreads();
            float v0 = red[0][0][rrow][rc] + red[1][0][rrow][rc] + red[2][0][rrow][rc] +
                       red[3][0][rrow][rc] + bias3_a;
            float v1 = red[0][1][rrow][rc] + red[1][1][rrow][rc] + red[2][1][rrow][rc] +
                       red[3][1][rrow][rc] + bias3_b;
            gbuf[rrow][rc] = v0;
            gbuf[rrow][rc + 16] = v1;
            __syncthreads();
            if (tid < 128) {
                int r = tid >> 3, j = tid & 7;
                float gi = gbuf[r][j], gf = gbuf[r][8 + j], gg = gbuf[r][16 + j], go = gbuf[r][24 + j];
                float cn = sigm(gf) * cb2[r][j] + sigm(gi) * tanh_(gg);
                cb2[r][j] = cn;
                float h = sigm(go) * tanh_(cn);
                st_bf16(&h2b[(size_t)cbuf * (B_ * H_) + (size_t)(g * 16 + r) * H_ + wg * 8 + j], h);
                if (t == S_ - 1) {
                    out[HO2 + (size_t)(g * 16 + r) * H_ + wg * 8 + j] = h;
                    out[CO2 + (size_t)(g * 16 + r) * H_ + wg * 8 + j] = cn;
                }
            }
        }
        bar_arrive(arr, wg, tid, ++bt);
        // prefetch x(t+1) while polling (plain cached loads — x is read-only input)
        if (wave == 0) {
            const int tn = (t + 1 < S_) ? (t + 1) : (S_ - 1);
            const float* xp = x + ((size_t)b_ * S_ + tn) * F_ + quad * 8;
#pragma unroll
            for (int ki = 0; ki < 4; ++ki) {
                f32x4 x0 = *(const f32x4*)(xp + ki * 32);
                f32x4 x1 = *(const f32x4*)(xp + ki * 32 + 4);
                bf16x8 a;
#pragma unroll
                for (int i = 0; i < 4; ++i) { a[i] = (bf16_t)x0[i]; a[4 + i] = (bf16_t)x1[i]; }
                xpre[ki] = a;
            }
        }
        // loop head does bar_wait(bt) -> P1 of t+1
    }
}

extern "C" void kernel_launch(void* const* d_in, const int* in_sizes, int n_in, void* d_out,
                              int out_size, void* d_ws, size_t ws_size, hipStream_t stream) {
    const float* x = (const float*)d_in[0];
    const float* pg0 = (const float*)d_in[1];
    const float* h1i = (const float*)d_in[2];
    const float* c1i = (const float*)d_in[3];
    const float* h2i = (const float*)d_in[4];
    const float* c2i = (const float*)d_in[5];
    const float* Wfc1 = (const float*)d_in[6];
    const float* bfc1 = (const float*)d_in[7];
    const float* Wih1 = (const float*)d_in[8];
    const float* Whh1 = (const float*)d_in[9];
    const float* b1 = (const float*)d_in[10];
    const float* Wih2 = (const float*)d_in[11];
    const float* Whh2 = (const float*)d_in[12];
    const float* b2g = (const float*)d_in[13];
    const float* Wfc2 = (const float*)d_in[14];
    const float* bfc2 = (const float*)d_in[15];
    uint8_t* ws = (uint8_t*)d_ws;
    float* out = (float*)d_out;

    k_init<<<dim3(128), dim3(256), 0, stream>>>(pg0, h1i, h2i, ws);
    k_fuse<<<dim3(512), dim3(128), 0, stream>>>(Wfc1, bfc1, Wfc2, bfc2, ws);
    k_frags<<<dim3(2496), dim3(256), 0, stream>>>(Wfc1, Wih1, Whh1, Wih2, Whh2, Wfc2, ws);
    k_rnn<<<dim3(256), dim3(256), 0, stream>>>(x, c1i, c2i, bfc1, b1, b2g, bfc2, ws, out);
}